// Round 13
// baseline (105.824 us; speedup 1.0000x reference)
//
#include <hip/hip_runtime.h>

#define N_ 64
#define C_ 64
#define T_ 256
#define V_ 25
#define R_ 8
#define O_ 64
constexpr int TV = T_ * V_;           // 6400
constexpr float INV_T = 1.0f / (float)T_;
constexpr int TC = 16;                // t's per fused block
constexpr int NPOS = TC * V_;         // 400
constexpr int NT = NPOS / 16;         // 25 MFMA N-tiles
constexpr int DP = 32;                // padded u,v extent of dT
constexpr int UPAD = 40;              // u slots per (o,t) row in x3b
constexpr int X3S = 16 * UPAD + 8;    // 648 halfwords per o_local
constexpr int CH = 32;                // c-half in k_prep
constexpr int LROW = 402;             // padded f32 row (8B-aligned, bank-clean)

typedef __attribute__((ext_vector_type(8))) short s8v;   // 8 bf16
typedef __attribute__((ext_vector_type(4))) float f4v;   // MFMA acc / float4
typedef __attribute__((ext_vector_type(2))) float f2v;

__device__ __forceinline__ unsigned short f2bf(float f) {   // RNE f32->bf16
    union { float f; unsigned u; } v; v.f = f;
    unsigned r = v.u + 0x7FFFu + ((v.u >> 16) & 1u);
    return (unsigned short)(r >> 16);
}

// -------- k_prep: per (n,tc): stage 32-c half of x in LDS (f32), fuse
//   (a) temporal-mean partials -> atomicAdd xm  (replaces k_mean)
//   (b) transpose -> xT[pos][c] bf16, stored in THIS block's d_out region:
//       byte L in [0,51200) -> out[n] + tc*1600 + (L/1600)*25600 + L%1600.
__global__ __launch_bounds__(256) void k_prep(const float* __restrict__ x,
                                              float* __restrict__ xm,
                                              float* out) {
    __shared__ float lx[CH * LROW];         // 51456 B
    const int n   = blockIdx.y;
    const int tc  = blockIdx.x;
    const int tid = threadIdx.x;
    const float* xb = x + (size_t)n * C_ * TV + tc * NPOS;
    char* xTb = (char*)out + (size_t)n * O_ * TV * 4 + (size_t)tc * 1600;

    #pragma unroll 1
    for (int kh = 0; kh < 2; ++kh) {
        // stage: 32 c rows x 100 float4, coalesced; write as 2x b64 (8B-aligned)
        #pragma unroll 1
        for (int i = 0; i < 13; ++i) {
            const int s = i * 256 + tid;
            if (s < CH * 100) {
                const int c = s / 100, p4 = s - c * 100;
                const f4v v = *(const f4v*)(xb + (size_t)(kh * CH + c) * TV + p4 * 4);
                float* p = &lx[c * LROW + p4 * 4];
                *(f2v*)p = f2v{v[0], v[1]};
                *(f2v*)(p + 2) = f2v{v[2], v[3]};
            }
        }
        __syncthreads();

        // mean partials: 800 (c,v) pairs, sum 16 t's each
        #pragma unroll 1
        for (int i = 0; i < 4; ++i) {
            const int p = i * 256 + tid;
            if (p < CH * V_) {
                const int c = p / V_, v = p - c * V_;
                float s = 0.f;
                #pragma unroll
                for (int t = 0; t < TC; ++t) s += lx[c * LROW + t * V_ + v];
                atomicAdd(&xm[(size_t)n * C_ * V_ + (kh * CH + c) * V_ + v], s * INV_T);
            }
        }

        // emit xT: 1600 b128 items; item -> pos=it/4, ch=it%4 (8 c's each)
        #pragma unroll 1
        for (int i = 0; i < 7; ++i) {
            const int it = i * 256 + tid;
            if (it < 1600) {
                const int pos = it >> 2, ch = it & 3;
                s8v pk;
                #pragma unroll
                for (int j = 0; j < 8; ++j)
                    pk[j] = (short)f2bf(lx[(ch * 8 + j) * LROW + pos]);
                const int L = pos * 128 + kh * 64 + ch * 16;
                const int row = L / 1600, off = L - row * 1600;
                *(s8v*)(xTb + (size_t)row * (TV * 4) + off) = pk;
            }
        }
        __syncthreads();
    }
}

// -------- k_dmat: dT[n][o][v][u] = d(u,v) bf16, zero-padded to 32x32.
__global__ __launch_bounds__(256) void k_dmat(const float* __restrict__ xm,
                                              const float* __restrict__ A,
                                              const float* __restrict__ w1,
                                              const float* __restrict__ b1,
                                              const float* __restrict__ w2,
                                              const float* __restrict__ b2,
                                              const float* __restrict__ w4,
                                              const float* __restrict__ b4,
                                              unsigned short* __restrict__ dT) {
    __shared__ float xms[C_][V_];
    __shared__ float x1s[R_][V_];
    __shared__ float x2s[R_][V_];
    const int n  = blockIdx.x;
    const int og = blockIdx.y * 8;
    const int tid = threadIdx.x;

    for (int i = tid; i < C_ * V_; i += 256)
        xms[i / V_][i % V_] = xm[(size_t)n * C_ * V_ + i];
    __syncthreads();

    for (int i = tid; i < 2 * R_ * V_; i += 256) {
        const int j = i % (R_ * V_);
        const int r = j / V_, v = j % V_;
        const bool first = (i < R_ * V_);
        const float* w = first ? w1 : w2;
        float acc = first ? b1[r] : b2[r];
        #pragma unroll
        for (int c = 0; c < C_; ++c) acc += w[r * C_ + c] * xms[c][v];
        if (first) x1s[r][v] = acc;
        else       x2s[r][v] = acc;
    }
    __syncthreads();

    unsigned short* dn = dT + (size_t)n * O_ * DP * DP;
    for (int p = tid; p < DP * DP; p += 256) {       // p = v*32+u
        const int v = p >> 5, u = p & 31;
        if (u < V_ && v < V_) {
            float adjr[R_];
            #pragma unroll
            for (int r = 0; r < R_; ++r) adjr[r] = tanhf(x1s[r][u] - x2s[r][v]);
            const float a = A[u * V_ + v];
            #pragma unroll
            for (int oo = 0; oo < 8; ++oo) {
                const int o = og + oo;
                float acc = b4[o];
                #pragma unroll
                for (int r = 0; r < R_; ++r) acc = fmaf(w4[o * R_ + r], adjr[r], acc);
                dn[(size_t)o * DP * DP + p] = f2bf(acc + a);   // ALPHA == 1
            }
        } else {
            #pragma unroll
            for (int oo = 0; oo < 8; ++oo)
                dn[(size_t)(og + oo) * DP * DP + p] = 0;
        }
    }
}

// -------- k_F v6: B-frags = single b128 loads from pre-transposed xT
//          (in this block's own d_out region); GEMM2 dT b128; x3b-only LDS.
//          `io` is both xT source and out dest (same pointer -> no restrict).
__global__ __launch_bounds__(512) void k_F(const float* __restrict__ w3,
                                           const float* __restrict__ b3,
                                           const unsigned short* __restrict__ dT,
                                           float* io) {
    __shared__ __align__(16) unsigned short x3b[16 * X3S];        // 20736 B

    const int n    = blockIdx.y;
    const int tc   = blockIdx.x;
    const int tid  = threadIdx.x;
    const int lane = tid & 63;
    const int wave = tid >> 6;      // 0..7
    const int l16  = lane & 15;
    const int lg   = lane >> 4;     // 0..3

    // zero x3b u-pad [24,32): [25,32) must be 0 for GEMM2's K=32
    if (tid < 256) {
        const int o_l = tid >> 4, t = tid & 15;
        *(s8v*)&x3b[o_l * X3S + t * UPAD + 24] = (s8v)0;
    }
    __syncthreads();

    // ---- hoist B-frags: 8 independent b128 loads from xT
    const char* xTb = (const char*)io + (size_t)n * O_ * TV * 4 + (size_t)tc * 1600;
    s8v bfr[4][2];
    #pragma unroll
    for (int i = 0; i < 4; ++i) {
        const int nt = wave + 8 * i;
        if (nt < NT) {
            const int pos = nt * 16 + l16;
            #pragma unroll
            for (int kh = 0; kh < 2; ++kh) {
                const int L = pos * 128 + kh * 64 + lg * 16;
                const int row = L / 1600, off = L - row * 1600;
                bfr[i][kh] = *(const s8v*)(xTb + (size_t)row * (TV * 4) + off);
            }
        }
    }

    const unsigned short* dn = dT + (size_t)n * O_ * DP * DP;
    float* on = io + (size_t)n * O_ * TV + tc * NPOS;

    #pragma unroll 1
    for (int h = 0; h < 4; ++h) {               // o-quarter: o = h*16 .. h*16+15
        // A-frags (w3 L1/L2-resident)
        s8v afr[2];
        #pragma unroll
        for (int kh = 0; kh < 2; ++kh) {
            const float* wp = w3 + (h * 16 + l16) * C_ + kh * 32 + lg * 8;
            s8v f;
            #pragma unroll
            for (int j = 0; j < 8; ++j) f[j] = (short)f2bf(wp[j]);
            afr[kh] = f;
        }
        const f4v b3h = *(const f4v*)(b3 + h * 16 + lg * 4);

        // GEMM1 quarter
        #pragma unroll
        for (int i = 0; i < 4; ++i) {
            const int nt = wave + 8 * i;
            if (nt < NT) {
                const int pos = nt * 16 + l16;
                const int t = pos / 25, u = pos - 25 * t;
                f4v acc = (f4v)0.f;
                acc = __builtin_amdgcn_mfma_f32_16x16x32_bf16(afr[0], bfr[i][0], acc, 0, 0, 0);
                acc = __builtin_amdgcn_mfma_f32_16x16x32_bf16(afr[1], bfr[i][1], acc, 0, 0, 0);
                #pragma unroll
                for (int r = 0; r < 4; ++r)
                    x3b[(lg * 4 + r) * X3S + t * UPAD + u] = f2bf(acc[r] + b3h[r]);
            }
        }
        __syncthreads();   // B1: x3b ready (h=0: also fences xT reads vs stores)

        // GEMM2 quarter: wave owns o_l = wave*2 + {0,1}
        #pragma unroll
        for (int oo = 0; oo < 2; ++oo) {
            const int o_l = wave * 2 + oo;
            const int o_g = h * 16 + o_l;
            const unsigned short* dp = dn + (size_t)o_g * DP * DP;
            const s8v bv0 = *(const s8v*)(dp + l16 * DP + lg * 8);
            const s8v bv1 = *(const s8v*)(dp + (16 + l16) * DP + lg * 8);
            const s8v av  = *(const s8v*)&x3b[o_l * X3S + l16 * UPAD + lg * 8];
            f4v c0 = (f4v)0.f, c1 = (f4v)0.f;
            c0 = __builtin_amdgcn_mfma_f32_16x16x32_bf16(av, bv0, c0, 0, 0, 0);
            c1 = __builtin_amdgcn_mfma_f32_16x16x32_bf16(av, bv1, c1, 0, 0, 0);
            float* ob = on + (size_t)o_g * TV;
            #pragma unroll
            for (int r = 0; r < 4; ++r) {
                const int t = lg * 4 + r;                       // C: row=t, col=v
                ob[t * 25 + l16] = c0[r];
                if (l16 < 9) ob[t * 25 + 16 + l16] = c1[r];
            }
        }
        __syncthreads();   // B2: protect x3b before next quarter's GEMM1
    }
}

extern "C" void kernel_launch(void* const* d_in, const int* in_sizes, int n_in,
                              void* d_out, int out_size, void* d_ws, size_t ws_size,
                              hipStream_t stream) {
    const float* x  = (const float*)d_in[0];
    const float* A  = (const float*)d_in[1];
    const float* w1 = (const float*)d_in[2];
    const float* b1 = (const float*)d_in[3];
    const float* w2 = (const float*)d_in[4];
    const float* b2 = (const float*)d_in[5];
    const float* w3 = (const float*)d_in[6];
    const float* b3 = (const float*)d_in[7];
    const float* w4 = (const float*)d_in[8];
    const float* b4 = (const float*)d_in[9];

    float* out = (float*)d_out;
    float* xm  = (float*)d_ws;                                          // 0.41 MB f32
    unsigned short* dTm = (unsigned short*)(xm + (size_t)N_ * C_ * V_); // 8.4 MB bf16

    hipMemsetAsync(xm, 0, (size_t)N_ * C_ * V_ * sizeof(float), stream);
    k_prep<<<dim3(T_ / TC, N_), 256, 0, stream>>>(x, xm, out);
    k_dmat<<<dim3(N_, 8), 256, 0, stream>>>(xm, A, w1, b1, w2, b2, w4, b4, dTm);
    k_F<<<dim3(T_ / TC, N_), 512, 0, stream>>>(w3, b3, dTm, out);
}

// Round 14
// 97.447 us; speedup vs baseline: 1.0860x; 1.0860x over previous
//
#include <hip/hip_runtime.h>

#define N_ 64
#define C_ 64
#define T_ 256
#define V_ 25
#define R_ 8
#define O_ 64
constexpr int TV = T_ * V_;           // 6400
constexpr float INV_T = 1.0f / (float)T_;
constexpr int TC = 16;                // t's per fused block
constexpr int NPOS = TC * V_;         // 400
constexpr int NT = NPOS / 16;         // 25 MFMA N-tiles
constexpr int DP = 32;                // padded u,v extent of dT
constexpr int UPAD = 40;              // u slots per (o,t) row in x3b
constexpr int X3S = 16 * UPAD + 8;    // 648 halfwords per o_local
constexpr int LS = 402;               // LDS row stride (halfwords); 402%8==2 ->
                                      // 8-c-apart reads step banks by 8 (no pileup)

typedef __attribute__((ext_vector_type(8))) short s8v;   // 8 bf16
typedef __attribute__((ext_vector_type(4))) float f4v;   // MFMA acc / float4

__device__ __forceinline__ unsigned short f2bf(float f) {   // RNE f32->bf16
    union { float f; unsigned u; } v; v.f = f;
    unsigned r = v.u + 0x7FFFu + ((v.u >> 16) & 1u);
    return (unsigned short)(r >> 16);
}
__device__ __forceinline__ unsigned pk2(float a, float b) { // 2 bf16 in a u32
    return (unsigned)f2bf(a) | ((unsigned)f2bf(b) << 16);
}
__device__ __forceinline__ float bf2f(unsigned short h) {
    union { unsigned u; float f; } v; v.u = (unsigned)h << 16; return v.f;
}

// -------- k_prep v2: per (n,tc): stage ALL 64 c's as bf16 in LDS (one pass),
//   then (a) mean partials -> atomicAdd xm, (b) emit xT[pos][c] bf16 into this
//   block's d_out region (same contract as r13: L = pos*128 + c0*2;
//   out[n] + tc*1600 + (L/1600)*TV*4 + L%1600).
//   512 thr, 51.5 KB LDS -> 3 blocks/CU; ONE barrier; stride-402 bank fix.
__global__ __launch_bounds__(512) void k_prep(const float* __restrict__ x,
                                              float* __restrict__ xm,
                                              float* out) {
    __shared__ unsigned short lx[C_ * LS];      // 51456 B
    const int n   = blockIdx.y;
    const int tc  = blockIdx.x;
    const int tid = threadIdx.x;
    const float* xb = x + (size_t)n * C_ * TV + tc * NPOS;
    char* xTb = (char*)out + (size_t)n * O_ * TV * 4 + (size_t)tc * 1600;

    // phase 1: 6400 float4 items (64 c x 100), coalesced reads, packed-u32 LDS
    // writes (stride 804B is 4B-aligned; consecutive lanes -> consecutive banks)
    #pragma unroll 4
    for (int i = 0; i < 13; ++i) {
        const int s = i * 512 + tid;
        if (s < C_ * 100) {
            const int c = s / 100, p4 = s - c * 100;
            const f4v v = *(const f4v*)(xb + (size_t)c * TV + p4 * 4);
            unsigned* p = (unsigned*)&lx[c * LS + p4 * 4];
            p[0] = pk2(v[0], v[1]);
            p[1] = pk2(v[2], v[3]);
        }
    }
    __syncthreads();

    // phase 2: mean partials: 1600 (c,v) pairs, sum 16 t's each, one atomic
    #pragma unroll
    for (int i = 0; i < 4; ++i) {
        const int p = i * 512 + tid;
        if (p < C_ * V_) {
            const int c = p / V_, v = p - c * V_;
            float s = 0.f;
            #pragma unroll
            for (int t = 0; t < TC; ++t) s += bf2f(lx[c * LS + t * V_ + v]);
            atomicAdd(&xm[(size_t)n * C_ * V_ + p], s * INV_T);
        }
    }

    // phase 3 (no barrier needed - LDS read-only from here): emit xT.
    // 3200 b128 items: pos=it>>3, ch=it&7 (c0=ch*8) -> stores are contiguous
    // 16B runs across lanes; LDS reads: banks step 8 per ch (stride-402 fix).
    #pragma unroll 2
    for (int i = 0; i < 7; ++i) {
        const int it = i * 512 + tid;
        if (it < 3200) {
            const int pos = it >> 3, ch = it & 7;
            s8v pk;
            #pragma unroll
            for (int j = 0; j < 8; ++j)
                pk[j] = (short)lx[(ch * 8 + j) * LS + pos];
            const int L = pos * 128 + ch * 16;
            const int row = L / 1600, off = L - row * 1600;
            *(s8v*)(xTb + (size_t)row * (TV * 4) + off) = pk;
        }
    }
}

// -------- k_dmat: dT[n][o][v][u] = d(u,v) bf16, zero-padded to 32x32. (r13)
__global__ __launch_bounds__(256) void k_dmat(const float* __restrict__ xm,
                                              const float* __restrict__ A,
                                              const float* __restrict__ w1,
                                              const float* __restrict__ b1,
                                              const float* __restrict__ w2,
                                              const float* __restrict__ b2,
                                              const float* __restrict__ w4,
                                              const float* __restrict__ b4,
                                              unsigned short* __restrict__ dT) {
    __shared__ float xms[C_][V_];
    __shared__ float x1s[R_][V_];
    __shared__ float x2s[R_][V_];
    const int n  = blockIdx.x;
    const int og = blockIdx.y * 8;
    const int tid = threadIdx.x;

    for (int i = tid; i < C_ * V_; i += 256)
        xms[i / V_][i % V_] = xm[(size_t)n * C_ * V_ + i];
    __syncthreads();

    for (int i = tid; i < 2 * R_ * V_; i += 256) {
        const int j = i % (R_ * V_);
        const int r = j / V_, v = j % V_;
        const bool first = (i < R_ * V_);
        const float* w = first ? w1 : w2;
        float acc = first ? b1[r] : b2[r];
        #pragma unroll
        for (int c = 0; c < C_; ++c) acc += w[r * C_ + c] * xms[c][v];
        if (first) x1s[r][v] = acc;
        else       x2s[r][v] = acc;
    }
    __syncthreads();

    unsigned short* dn = dT + (size_t)n * O_ * DP * DP;
    for (int p = tid; p < DP * DP; p += 256) {       // p = v*32+u
        const int v = p >> 5, u = p & 31;
        if (u < V_ && v < V_) {
            float adjr[R_];
            #pragma unroll
            for (int r = 0; r < R_; ++r) adjr[r] = tanhf(x1s[r][u] - x2s[r][v]);
            const float a = A[u * V_ + v];
            #pragma unroll
            for (int oo = 0; oo < 8; ++oo) {
                const int o = og + oo;
                float acc = b4[o];
                #pragma unroll
                for (int r = 0; r < R_; ++r) acc = fmaf(w4[o * R_ + r], adjr[r], acc);
                dn[(size_t)o * DP * DP + p] = f2bf(acc + a);   // ALPHA == 1
            }
        } else {
            #pragma unroll
            for (int oo = 0; oo < 8; ++oo)
                dn[(size_t)(og + oo) * DP * DP + p] = 0;
        }
    }
}

// -------- k_F v6 (r13, validated ~23us): B-frags = single b128 loads from
//          pre-transposed xT (in this block's own d_out region); x3b-only LDS.
__global__ __launch_bounds__(512) void k_F(const float* __restrict__ w3,
                                           const float* __restrict__ b3,
                                           const unsigned short* __restrict__ dT,
                                           float* io) {
    __shared__ __align__(16) unsigned short x3b[16 * X3S];        // 20736 B

    const int n    = blockIdx.y;
    const int tc   = blockIdx.x;
    const int tid  = threadIdx.x;
    const int lane = tid & 63;
    const int wave = tid >> 6;      // 0..7
    const int l16  = lane & 15;
    const int lg   = lane >> 4;     // 0..3

    // zero x3b u-pad [24,32): [25,32) must be 0 for GEMM2's K=32
    if (tid < 256) {
        const int o_l = tid >> 4, t = tid & 15;
        *(s8v*)&x3b[o_l * X3S + t * UPAD + 24] = (s8v)0;
    }
    __syncthreads();

    // ---- hoist B-frags: 8 independent b128 loads from xT
    const char* xTb = (const char*)io + (size_t)n * O_ * TV * 4 + (size_t)tc * 1600;
    s8v bfr[4][2];
    #pragma unroll
    for (int i = 0; i < 4; ++i) {
        const int nt = wave + 8 * i;
        if (nt < NT) {
            const int pos = nt * 16 + l16;
            #pragma unroll
            for (int kh = 0; kh < 2; ++kh) {
                const int L = pos * 128 + kh * 64 + lg * 16;
                const int row = L / 1600, off = L - row * 1600;
                bfr[i][kh] = *(const s8v*)(xTb + (size_t)row * (TV * 4) + off);
            }
        }
    }

    const unsigned short* dn = dT + (size_t)n * O_ * DP * DP;
    float* on = io + (size_t)n * O_ * TV + tc * NPOS;

    #pragma unroll 1
    for (int h = 0; h < 4; ++h) {               // o-quarter: o = h*16 .. h*16+15
        // A-frags (w3 L1/L2-resident)
        s8v afr[2];
        #pragma unroll
        for (int kh = 0; kh < 2; ++kh) {
            const float* wp = w3 + (h * 16 + l16) * C_ + kh * 32 + lg * 8;
            s8v f;
            #pragma unroll
            for (int j = 0; j < 8; ++j) f[j] = (short)f2bf(wp[j]);
            afr[kh] = f;
        }
        const f4v b3h = *(const f4v*)(b3 + h * 16 + lg * 4);

        // GEMM1 quarter
        #pragma unroll
        for (int i = 0; i < 4; ++i) {
            const int nt = wave + 8 * i;
            if (nt < NT) {
                const int pos = nt * 16 + l16;
                const int t = pos / 25, u = pos - 25 * t;
                f4v acc = (f4v)0.f;
                acc = __builtin_amdgcn_mfma_f32_16x16x32_bf16(afr[0], bfr[i][0], acc, 0, 0, 0);
                acc = __builtin_amdgcn_mfma_f32_16x16x32_bf16(afr[1], bfr[i][1], acc, 0, 0, 0);
                #pragma unroll
                for (int r = 0; r < 4; ++r)
                    x3b[(lg * 4 + r) * X3S + t * UPAD + u] = f2bf(acc[r] + b3h[r]);
            }
        }
        __syncthreads();   // B1: x3b ready (h=0: also fences xT reads vs stores)

        // GEMM2 quarter: wave owns o_l = wave*2 + {0,1}
        #pragma unroll
        for (int oo = 0; oo < 2; ++oo) {
            const int o_l = wave * 2 + oo;
            const int o_g = h * 16 + o_l;
            const unsigned short* dp = dn + (size_t)o_g * DP * DP;
            const s8v bv0 = *(const s8v*)(dp + l16 * DP + lg * 8);
            const s8v bv1 = *(const s8v*)(dp + (16 + l16) * DP + lg * 8);
            const s8v av  = *(const s8v*)&x3b[o_l * X3S + l16 * UPAD + lg * 8];
            f4v c0 = (f4v)0.f, c1 = (f4v)0.f;
            c0 = __builtin_amdgcn_mfma_f32_16x16x32_bf16(av, bv0, c0, 0, 0, 0);
            c1 = __builtin_amdgcn_mfma_f32_16x16x32_bf16(av, bv1, c1, 0, 0, 0);
            float* ob = on + (size_t)o_g * TV;
            #pragma unroll
            for (int r = 0; r < 4; ++r) {
                const int t = lg * 4 + r;                       // C: row=t, col=v
                ob[t * 25 + l16] = c0[r];
                if (l16 < 9) ob[t * 25 + 16 + l16] = c1[r];
            }
        }
        __syncthreads();   // B2: protect x3b before next quarter's GEMM1
    }
}

extern "C" void kernel_launch(void* const* d_in, const int* in_sizes, int n_in,
                              void* d_out, int out_size, void* d_ws, size_t ws_size,
                              hipStream_t stream) {
    const float* x  = (const float*)d_in[0];
    const float* A  = (const float*)d_in[1];
    const float* w1 = (const float*)d_in[2];
    const float* b1 = (const float*)d_in[3];
    const float* w2 = (const float*)d_in[4];
    const float* b2 = (const float*)d_in[5];
    const float* w3 = (const float*)d_in[6];
    const float* b3 = (const float*)d_in[7];
    const float* w4 = (const float*)d_in[8];
    const float* b4 = (const float*)d_in[9];

    float* out = (float*)d_out;
    float* xm  = (float*)d_ws;                                          // 0.41 MB f32
    unsigned short* dTm = (unsigned short*)(xm + (size_t)N_ * C_ * V_); // 8.4 MB bf16

    hipMemsetAsync(xm, 0, (size_t)N_ * C_ * V_ * sizeof(float), stream);
    k_prep<<<dim3(T_ / TC, N_), 512, 0, stream>>>(x, xm, out);
    k_dmat<<<dim3(N_, 8), 256, 0, stream>>>(xm, A, w1, b1, w2, b2, w4, b4, dTm);
    k_F<<<dim3(T_ / TC, N_), 512, 0, stream>>>(w3, b3, dTm, out);
}